// Round 1
// baseline (590.303 us; speedup 1.0000x reference)
//
#include <hip/hip_runtime.h>

// Entmax-1.5 over last axis, exact via Newton root-find on
//   f(tau) = sum_i max(x_i - tau, 0)^2 - 1  (unique root == sort-algorithm tau*)
// One wave (64 lanes) per row of S=2048; 32 elems/lane in registers.
// No LDS, no __syncthreads — all reductions are wave shuffles.

#define NEG_FILL (-1.0e4f)

static constexpr int S_DIM = 2048;
static constexpr int WAVES_PER_BLOCK = 4;       // 256-thread blocks
static constexpr int ELEMS = S_DIM / 64;        // 32 floats per lane
static constexpr int VEC = ELEMS / 4;           // 8 float4 loads per lane

__global__ __launch_bounds__(256) void entmax15_kernel(
    const float* __restrict__ scores,
    const int*   __restrict__ mask,
    float*       __restrict__ out,
    int nrows)
{
    const int lane = threadIdx.x & 63;
    const int wave = threadIdx.x >> 6;
    const int row  = blockIdx.x * WAVES_PER_BLOCK + wave;
    if (row >= nrows) return;

    const size_t base = (size_t)row * S_DIM;
    const float4* __restrict__ srow = (const float4*)(scores + base);
    const int4*   __restrict__ mrow = (const int4*)(mask + base);
    float4*       __restrict__ orow = (float4*)(out + base);

    // ---- load + mask + row max (in registers) ----
    float x[ELEMS];
    float rmax = -3.402823466e38f;
#pragma unroll
    for (int j = 0; j < VEC; ++j) {
        const float4 s = srow[lane + 64 * j];
        const int4   m = mrow[lane + 64 * j];
        float v0 = m.x ? s.x : NEG_FILL;
        float v1 = m.y ? s.y : NEG_FILL;
        float v2 = m.z ? s.z : NEG_FILL;
        float v3 = m.w ? s.w : NEG_FILL;
        x[4 * j + 0] = v0;
        x[4 * j + 1] = v1;
        x[4 * j + 2] = v2;
        x[4 * j + 3] = v3;
        rmax = fmaxf(rmax, fmaxf(fmaxf(v0, v1), fmaxf(v2, v3)));
    }
#pragma unroll
    for (int off = 32; off >= 1; off >>= 1)
        rmax = fmaxf(rmax, __shfl_xor(rmax, off, 64));

    // ---- alpha=1.5 transform: x = (x - max) * 0.5  (so max(x) == 0) ----
#pragma unroll
    for (int i = 0; i < ELEMS; ++i)
        x[i] = (x[i] - rmax) * 0.5f;

    // ---- Newton on f(tau) = sum max(x - tau, 0)^2 - 1, from tau0 = -1 ----
    // Monotone convergence from below (f convex, decreasing); G >= 1 always.
    float tau = -1.0f;
#pragma unroll 1
    for (int it = 0; it < 24; ++it) {
        float F = 0.0f, G = 0.0f;
#pragma unroll
        for (int i = 0; i < ELEMS; ++i) {
            float y = fmaxf(x[i] - tau, 0.0f);
            F = fmaf(y, y, F);
            G += y;
        }
#pragma unroll
        for (int off = 32; off >= 1; off >>= 1) {
            F += __shfl_xor(F, off, 64);
            G += __shfl_xor(G, off, 64);
        }
        float dt = (F - 1.0f) / (2.0f * G);
        tau += dt;
        // butterfly gives bitwise-identical F,G on all lanes -> uniform branch
        if (!(fabsf(dt) > 1e-7f)) break;
    }

    // ---- epilogue: p = max(x - tau, 0)^2, coalesced float4 stores ----
#pragma unroll
    for (int j = 0; j < VEC; ++j) {
        float y0 = fmaxf(x[4 * j + 0] - tau, 0.0f);
        float y1 = fmaxf(x[4 * j + 1] - tau, 0.0f);
        float y2 = fmaxf(x[4 * j + 2] - tau, 0.0f);
        float y3 = fmaxf(x[4 * j + 3] - tau, 0.0f);
        float4 o;
        o.x = y0 * y0;
        o.y = y1 * y1;
        o.z = y2 * y2;
        o.w = y3 * y3;
        orow[lane + 64 * j] = o;
    }
}

extern "C" void kernel_launch(void* const* d_in, const int* in_sizes, int n_in,
                              void* d_out, int out_size, void* d_ws, size_t ws_size,
                              hipStream_t stream) {
    const float* scores = (const float*)d_in[0];
    const int*   mask   = (const int*)d_in[1];
    float*       out    = (float*)d_out;

    const int nrows = in_sizes[0] / S_DIM;  // 32768
    const int grid  = (nrows + WAVES_PER_BLOCK - 1) / WAVES_PER_BLOCK;

    entmax15_kernel<<<grid, 256, 0, stream>>>(scores, mask, out, nrows);
}

// Round 2
// 584.165 us; speedup vs baseline: 1.0105x; 1.0105x over previous
//
#include <hip/hip_runtime.h>

// Entmax-1.5 over last axis. tau* is the root of
//   f(tau) = sum_i max(x_i - tau, 0)^2 - 1   (convex, piecewise quadratic, decreasing)
// Instead of Newton (tangent), solve the CURRENT PIECE's quadratic exactly each
// step (Michelot-style): with F = sum y^2, G = sum y, K = #{y>0} at current tau,
//   u = (F-1) / (G + sqrt(G^2 - K*(F-1)))        [exact in-piece root]
// - u >= Newton step (rationalization), so convergence is at least Newton-fast
// - terminates EXACTLY when the support set stabilizes (typ. 2-4 iterations;
//   all-equal row: 1 iteration vs ~15 for Newton)
// - disc<0 => root beyond piece end: fall back to Newton (still from-below safe);
//   from above (F<1) disc>0 always and convexity self-corrects.
// One wave per row of S=2048; 32 elems/lane in registers; shuffle reductions only.

#define NEG_FILL (-1.0e4f)

static constexpr int S_DIM = 2048;
static constexpr int WAVES_PER_BLOCK = 4;       // 256-thread blocks
static constexpr int ELEMS = S_DIM / 64;        // 32 floats per lane
static constexpr int VEC = ELEMS / 4;           // 8 float4 loads per lane

__global__ __launch_bounds__(256) void entmax15_kernel(
    const float* __restrict__ scores,
    const int*   __restrict__ mask,
    float*       __restrict__ out,
    int nrows)
{
    const int lane = threadIdx.x & 63;
    const int wave = threadIdx.x >> 6;
    const int row  = blockIdx.x * WAVES_PER_BLOCK + wave;
    if (row >= nrows) return;

    const size_t base = (size_t)row * S_DIM;
    const float4* __restrict__ srow = (const float4*)(scores + base);
    const int4*   __restrict__ mrow = (const int4*)(mask + base);
    float4*       __restrict__ orow = (float4*)(out + base);

    // ---- load + mask + row max (in registers) ----
    float x[ELEMS];
    float rmax = -3.402823466e38f;
#pragma unroll
    for (int j = 0; j < VEC; ++j) {
        const float4 s = srow[lane + 64 * j];
        const int4   m = mrow[lane + 64 * j];
        float v0 = m.x ? s.x : NEG_FILL;
        float v1 = m.y ? s.y : NEG_FILL;
        float v2 = m.z ? s.z : NEG_FILL;
        float v3 = m.w ? s.w : NEG_FILL;
        x[4 * j + 0] = v0;
        x[4 * j + 1] = v1;
        x[4 * j + 2] = v2;
        x[4 * j + 3] = v3;
        rmax = fmaxf(rmax, fmaxf(fmaxf(v0, v1), fmaxf(v2, v3)));
    }
#pragma unroll
    for (int off = 32; off >= 1; off >>= 1)
        rmax = fmaxf(rmax, __shfl_xor(rmax, off, 64));

    // ---- alpha=1.5 transform: x = (x - max) * 0.5  => max(x) == 0, tau* in [-1, 0) ----
    const float shift = -0.5f * rmax;
#pragma unroll
    for (int i = 0; i < ELEMS; ++i)
        x[i] = fmaf(0.5f, x[i], shift);

    // ---- piecewise-exact root iteration from tau0 = -1 ----
    float tau = -1.0f;
#pragma unroll 1
    for (int it = 0; it < 16; ++it) {
        float F = 0.0f, G = 0.0f, K = 0.0f;
#pragma unroll
        for (int i = 0; i < ELEMS; ++i) {
            float d = x[i] - tau;
            float y = fmaxf(d, 0.0f);
            F = fmaf(y, y, F);
            G += y;
            K += (d > 0.0f) ? 1.0f : 0.0f;
        }
#pragma unroll
        for (int off = 32; off >= 1; off >>= 1) {
            F += __shfl_xor(F, off, 64);
            G += __shfl_xor(G, off, 64);
            K += __shfl_xor(K, off, 64);
        }
        const float c = F - 1.0f;
        const float disc = fmaf(G, G, -K * c);
        // disc>0: exact in-piece root; else Newton fallback (from-below safe)
        const float denom = (disc > 0.0f) ? (G + sqrtf(disc)) : (2.0f * G);
        const float u = c / denom;
        tau += u;
        // F,G,K bitwise-identical across lanes (butterfly) -> wave-uniform branch
        if (!(fabsf(u) > 2e-7f)) break;
    }

    // ---- epilogue: p = max(x - tau, 0)^2, coalesced float4 stores ----
#pragma unroll
    for (int j = 0; j < VEC; ++j) {
        float y0 = fmaxf(x[4 * j + 0] - tau, 0.0f);
        float y1 = fmaxf(x[4 * j + 1] - tau, 0.0f);
        float y2 = fmaxf(x[4 * j + 2] - tau, 0.0f);
        float y3 = fmaxf(x[4 * j + 3] - tau, 0.0f);
        float4 o;
        o.x = y0 * y0;
        o.y = y1 * y1;
        o.z = y2 * y2;
        o.w = y3 * y3;
        orow[lane + 64 * j] = o;
    }
}

extern "C" void kernel_launch(void* const* d_in, const int* in_sizes, int n_in,
                              void* d_out, int out_size, void* d_ws, size_t ws_size,
                              hipStream_t stream) {
    const float* scores = (const float*)d_in[0];
    const int*   mask   = (const int*)d_in[1];
    float*       out    = (float*)d_out;

    const int nrows = in_sizes[0] / S_DIM;  // 32768
    const int grid  = (nrows + WAVES_PER_BLOCK - 1) / WAVES_PER_BLOCK;

    entmax15_kernel<<<grid, 256, 0, stream>>>(scores, mask, out, nrows);
}